// Round 8
// baseline (159.720 us; speedup 1.0000x reference)
//
#include <hip/hip_runtime.h>

typedef __bf16 bf16x8 __attribute__((ext_vector_type(8)));
typedef float f32x4 __attribute__((ext_vector_type(4)));
typedef unsigned short u16;
typedef unsigned int u32;

__device__ __forceinline__ u16 f2bf(float f) {
  u32 u = __builtin_bit_cast(u32, f);
  u32 r = (u + 0x7FFFu + ((u >> 16) & 1u)) >> 16;  // round-to-nearest-even
  return (u16)r;
}

// async global->LDS, 16B/lane. One call = 64 lanes x 16B = 1024B = 16 rows of
// a [..][32]-u16 tile. LDS dest = wave-uniform base + lane*16 (HW rule).
__device__ __forceinline__ void gload16(const u16* g, u16* lds_base) {
  __builtin_amdgcn_global_load_lds(
      (const __attribute__((address_space(1))) void*)g,
      (__attribute__((address_space(3))) void*)lds_base, 16, 0, 0);
}

// ---------------- fused cast fp32 -> bf16 for x, w_qkv, w_proj --------------
__global__ void cast_all(const float* __restrict__ x,  u16* __restrict__ xo,
                         const float* __restrict__ wq, u16* __restrict__ wqo,
                         const float* __restrict__ wp, u16* __restrict__ wpo) {
  const int NX = (2 * 2048 * 1024) / 4;   // float4 units
  const int NQ = (3072 * 1024) / 4;
  const int NP = (1024 * 1024) / 4;
  int i = blockIdx.x * blockDim.x + threadIdx.x;
  int stride = gridDim.x * blockDim.x;
  for (; i < NX + NQ + NP; i += stride) {
    const float4* s; uint2* d; int j;
    if (i < NX)            { s = (const float4*)x;  d = (uint2*)xo;  j = i; }
    else if (i < NX + NQ)  { s = (const float4*)wq; d = (uint2*)wqo; j = i - NX; }
    else                   { s = (const float4*)wp; d = (uint2*)wpo; j = i - NX - NQ; }
    float4 f = s[j];
    uint2 o;
    o.x = (u32)f2bf(f.x) | ((u32)f2bf(f.y) << 16);
    o.y = (u32)f2bf(f.z) | ((u32)f2bf(f.w) << 16);
    d[j] = o;
  }
}

// ---------------- bf16 MFMA GEMM: C[M,N] = A[M,K] * W[N,K]^T + bias ----------
// CHAMPION structure (44.0 us on GEMM1): BM x BN block tile, 4 waves (2x2),
// BK=32, double-buffered LDS, one barrier per K-iter, XCD-aware swizzle.
// R4 note: three schedules (this, 8-phase drain0, counted-vmcnt 3-buf) all
// measured 44-45 us at this shape -> deep-pipeline arc abandoned.
template<int OUT_BF16, int BM, int BN>
__global__ __launch_bounds__(256) void gemm_nt(
    const u16* __restrict__ A, const u16* __restrict__ W,
    const float* __restrict__ bias, void* __restrict__ Cout,
    int M, int N, int K)
{
  constexpr int MT = BM / 32;             // m-tiles per wave
  constexpr int NT = BN / 32;             // n-tiles per wave
  __shared__ u16 Alds[2][BM][32];
  __shared__ u16 Blds[2][BN][32];
  const int tid  = threadIdx.x;
  const int lane = tid & 63;
  const int wave = tid >> 6;
  const int wm = (wave >> 1) * (BM / 2);
  const int wn = (wave & 1) * (BN / 2);

  const int b    = blockIdx.x;
  const int xcd  = b & 7;
  const int slot = b >> 3;
  const int npx  = (N / BN) >> 3;         // n-columns owned per XCD
  const int m0 = (slot / npx) * BM;
  const int n0 = (xcd * npx + slot % npx) * BN;

  const int quad = lane >> 4;
  const int li   = lane & 15;

  const u16* ga = &A[(size_t)(m0 + wave * (BM / 4) + (lane >> 2)) * K + (lane & 3) * 8];
  const u16* gb = &W[(size_t)(n0 + wave * (BN / 4) + (lane >> 2)) * K + (lane & 3) * 8];

  auto stage = [&](int buf, int k0) {
#pragma unroll
    for (int i = 0; i < BM / 64; i++)
      gload16(ga + (size_t)i * 16 * K + k0, &Alds[buf][wave * (BM / 4) + i * 16][0]);
#pragma unroll
    for (int i = 0; i < BN / 64; i++)
      gload16(gb + (size_t)i * 16 * K + k0, &Blds[buf][wave * (BN / 4) + i * 16][0]);
  };

  f32x4 acc[MT][NT] = {};
  const int niter = K / 32;

  stage(0, 0);                            // prologue: tile 0 -> buf 0

#pragma unroll 2
  for (int kt = 0; kt < niter; kt++) {
    __syncthreads();                      // drains tile kt (one compute phase old)
    if (kt + 1 < niter) stage((kt + 1) & 1, (kt + 1) * 32);
    const int buf = kt & 1;
    bf16x8 af[MT], bfr[NT];
#pragma unroll
    for (int t = 0; t < MT; t++)
      af[t] = *(const bf16x8*)&Alds[buf][wm + t * 16 + li][quad * 8];
#pragma unroll
    for (int t = 0; t < NT; t++)
      bfr[t] = *(const bf16x8*)&Blds[buf][wn + t * 16 + li][quad * 8];
#pragma unroll
    for (int mt = 0; mt < MT; mt++)
#pragma unroll
      for (int nt = 0; nt < NT; nt++)
        acc[mt][nt] = __builtin_amdgcn_mfma_f32_16x16x32_bf16(af[mt], bfr[nt], acc[mt][nt], 0, 0, 0);
  }

#pragma unroll
  for (int mt = 0; mt < MT; mt++)
#pragma unroll
    for (int nt = 0; nt < NT; nt++) {
      int gn = n0 + wn + nt * 16 + li;
      float bv = bias[gn];
#pragma unroll
      for (int r = 0; r < 4; r++) {
        int gm = m0 + wm + mt * 16 + quad * 4 + r;
        float v = acc[mt][nt][r] + bv;
        if (OUT_BF16)
          ((u16*)Cout)[(size_t)gm * N + gn] = f2bf(v);
        else
          ((float*)Cout)[(size_t)gm * N + gn] = v;
      }
    }
}

// ---------------- sliding-window flash attention -----------------------------
// R7: 128-query / 8-wave blocks (was 64-query / 4-wave). Per 128 queries:
// 6 K/V stagings + 12 barriers (was 10 + 20) -> -40% staging & barrier
// traffic, -40% K/V global re-reads; +20% MFMA/softmax (masked fringe),
// which is cheap (MFMA floor ~2.6us). Per-thread staging halves: 512 threads
// cover a 64x64 tile with K = one uint4/thread, V = two uint2/thread
// (pair-packed transpose, b32 writes). Kernel internals per wave-tile are
// byte-equivalent to the proven R0 structure. XCD chunking kept (512%8==0):
// each XCD owns 4 heads x 16 qtiles = 2 MB KV working set, L2-resident.
__global__ __launch_bounds__(512, 4) void attn_kernel(const u16* __restrict__ qkv,
                                                      u16* __restrict__ aout)
{
  const int L = 2048, DQ = 3072, D = 1024;
  // chunked XCD transform on flat grid of 512 (512 % 8 == 0 -> bijective)
  const int bid  = blockIdx.x;
  const int wgid = (bid & 7) * 64 + (bid >> 3);
  const int qt = wgid & 15;          // 16 q-tiles of 128
  const int h  = (wgid >> 4) & 15;
  const int b  = wgid >> 8;
  const int q0 = qt * 128;
  const int tid  = threadIdx.x;
  const int lane = tid & 63;
  const int wave = tid >> 6;         // 0..7
  const int quad = lane >> 4;
  const int li   = lane & 15;

  __shared__ u16 Klds[64][68];       // [key][e], +4 pad
  __shared__ u16 Vt[64][68];         // [e][key], +4 pad
  __shared__ u16 Plds[8][16][68];    // per-wave P transpose buffer

  const u16* base = qkv + (size_t)b * L * DQ + h * 64;

  // Q A-frags direct from global: rows q0+16w+li
  bf16x8 qf[2];
  {
    const u16* qsrc = base + (size_t)(q0 + wave * 16 + li) * DQ;
    qf[0] = *(const bf16x8*)&qsrc[quad * 8];
    qf[1] = *(const bf16x8*)&qsrc[32 + quad * 8];
  }

  f32x4 O[4] = {};
  float lsum[4] = {0.f, 0.f, 0.f, 0.f};

  const float scale = 0.125f;        // 1/sqrt(64)
  const int gq = q0 + wave * 16 + quad * 4;  // + r

  // K staging: one uint4/thread (row sr, cols sc..sc+7)
  const int sr = tid >> 3, sc = (tid & 7) * 8;
  // V staging: pair scheme -- rows srv, srv+1 at cols scv..scv+3 (2x uint2)
  const int srv = (tid >> 4) * 2, scv = (tid & 15) * 4;
  const u16* ksbase = base + D;
  const u16* vsbase = base + 2 * D;
  uint4 kr; uint2 vr0, vr1;
  auto loadkv = [&](int t) {
    int kb = q0 - 256 + t * 64;
    kr  = *(const uint4*)&ksbase[(size_t)(kb + sr) * DQ + sc];
    vr0 = *(const uint2*)&vsbase[(size_t)(kb + srv) * DQ + scv];
    vr1 = *(const uint2*)&vsbase[(size_t)(kb + srv + 1) * DQ + scv];
  };

  // first tile with any valid key (kb >= 0 guaranteed by construction)
  const int t0 = (qt == 0) ? 4 : (qt == 1) ? 2 : 0;
  loadkv(t0);

  for (int t = t0; t < 6; t++) {
    const int kb = q0 - 256 + t * 64;
    __syncthreads();                 // protect LDS vs previous iter's reads
    *(uint4*)&Klds[sr][sc] = kr;
    {
      // V transpose: pack (key srv, key srv+1) for each e into one b32
      u32 a0[2] = {vr0.x, vr0.y};
      u32 a1[2] = {vr1.x, vr1.y};
#pragma unroll
      for (int j2 = 0; j2 < 2; j2++) {
        u32 lo0 = a0[j2] & 0xffffu, hi0 = a0[j2] >> 16;
        u32 lo1 = a1[j2] & 0xffffu, hi1 = a1[j2] >> 16;
        *(u32*)&Vt[scv + 2 * j2][srv]     = lo0 | (lo1 << 16);
        *(u32*)&Vt[scv + 2 * j2 + 1][srv] = hi0 | (hi1 << 16);
      }
    }
    __syncthreads();
    if (t + 1 < 6) loadkv(t + 1);    // prefetch overlaps with compute below

    // S = Q K^T : 16 rows x 64 keys per wave
    f32x4 sacc[4] = {};
#pragma unroll
    for (int nt = 0; nt < 4; nt++) {
      bf16x8 kf0 = *(const bf16x8*)&Klds[nt * 16 + li][quad * 8];
      bf16x8 kf1 = *(const bf16x8*)&Klds[nt * 16 + li][32 + quad * 8];
      sacc[nt] = __builtin_amdgcn_mfma_f32_16x16x32_bf16(qf[0], kf0, sacc[nt], 0, 0, 0);
      sacc[nt] = __builtin_amdgcn_mfma_f32_16x16x32_bf16(qf[1], kf1, sacc[nt], 0, 0, 0);
    }

    // mask + fixed-shift exp; accumulate per-lane partial sums; write P
#pragma unroll
    for (int nt = 0; nt < 4; nt++) {
      int gj = kb + nt * 16 + li;
#pragma unroll
      for (int r = 0; r < 4; r++) {
        bool masked = (gj > gq + r) || ((gq + r) - gj >= 256);
        float p = masked ? 0.f : __expf(sacc[nt][r] * scale - 12.f);
        lsum[r] += p;
        Plds[wave][quad * 4 + r][nt * 16 + li] = f2bf(p);
      }
    }

    // O += P V : A = P[m=li][k=key], B = Vt[n=e=li'][k=key] (b128 reads)
    bf16x8 pf0 = *(const bf16x8*)&Plds[wave][li][quad * 8];
    bf16x8 pf1 = *(const bf16x8*)&Plds[wave][li][32 + quad * 8];
#pragma unroll
    for (int nt = 0; nt < 4; nt++) {
      bf16x8 vb0 = *(const bf16x8*)&Vt[nt * 16 + li][quad * 8];
      bf16x8 vb1 = *(const bf16x8*)&Vt[nt * 16 + li][32 + quad * 8];
      O[nt] = __builtin_amdgcn_mfma_f32_16x16x32_bf16(pf0, vb0, O[nt], 0, 0, 0);
      O[nt] = __builtin_amdgcn_mfma_f32_16x16x32_bf16(pf1, vb1, O[nt], 0, 0, 0);
    }
  }

  // epilogue: reduce l over the 16-lane li group (once), then O/l -> aout
#pragma unroll
  for (int d = 1; d < 16; d <<= 1)
#pragma unroll
    for (int r = 0; r < 4; r++)
      lsum[r] += __shfl_xor(lsum[r], d, 64);
#pragma unroll
  for (int r = 0; r < 4; r++) {
    float inv = 1.f / lsum[r];
#pragma unroll
    for (int nt = 0; nt < 4; nt++)
      aout[(size_t)(b * L + gq + r) * D + h * 64 + nt * 16 + li] = f2bf(O[nt][r] * inv);
  }
}

// ---------------- launcher ---------------------------------------------------
extern "C" void kernel_launch(void* const* d_in, const int* in_sizes, int n_in,
                              void* d_out, int out_size, void* d_ws, size_t ws_size,
                              hipStream_t stream) {
  const float* x      = (const float*)d_in[0];
  const float* w_qkv  = (const float*)d_in[1];
  const float* b_qkv  = (const float*)d_in[2];
  const float* w_proj = (const float*)d_in[3];
  const float* b_proj = (const float*)d_in[4];
  float* out = (float*)d_out;

  char* ws = (char*)d_ws;
  u16* x_bf     = (u16*)(ws);                         //  8 MB: [4096,1024] bf16
  u16* wqkv_bf  = (u16*)(ws + ((size_t)8  << 20));    //  6 MB: [3072,1024] bf16
  u16* wproj_bf = (u16*)(ws + ((size_t)14 << 20));    //  2 MB: [1024,1024] bf16
  u16* qkv_bf   = (u16*)(ws + ((size_t)16 << 20));    // 24 MB: [4096,3072] bf16
  u16* attn_bf  = (u16*)(ws + ((size_t)40 << 20));    //  8 MB: [4096,1024] bf16

  cast_all<<<1024, 256, 0, stream>>>(x, x_bf, w_qkv, wqkv_bf, w_proj, wproj_bf);

  // GEMM1: 44.0 us champion (128x128, 768 blocks, 3/CU)
  gemm_nt<1, 128, 128><<<(4096 / 128) * (3072 / 128), 256, 0, stream>>>(
      x_bf, wqkv_bf, b_qkv, qkv_bf, 4096, 3072, 1024);

  // attn: 512 blocks x 512 threads (128 queries/block), chunked XCD swizzle
  attn_kernel<<<512, 512, 0, stream>>>(qkv_bf, attn_bf);

  // GEMM2 at 128x128
  gemm_nt<0, 128, 128><<<(4096 / 128) * (1024 / 128), 256, 0, stream>>>(
      attn_bf, wproj_bf, b_proj, out, 4096, 1024, 1024);
}

// Round 9
// 157.389 us; speedup vs baseline: 1.0148x; 1.0148x over previous
//
#include <hip/hip_runtime.h>

typedef __bf16 bf16x8 __attribute__((ext_vector_type(8)));
typedef float f32x4 __attribute__((ext_vector_type(4)));
typedef unsigned short u16;
typedef unsigned int u32;

__device__ __forceinline__ u16 f2bf(float f) {
  u32 u = __builtin_bit_cast(u32, f);
  u32 r = (u + 0x7FFFu + ((u >> 16) & 1u)) >> 16;  // round-to-nearest-even
  return (u16)r;
}

// async global->LDS, 16B/lane. One call = 64 lanes x 16B = 1024B.
// LDS dest = wave-uniform base + lane*16 (HW rule).
__device__ __forceinline__ void gload16(const u16* g, u16* lds_base) {
  __builtin_amdgcn_global_load_lds(
      (const __attribute__((address_space(1))) void*)g,
      (__attribute__((address_space(3))) void*)lds_base, 16, 0, 0);
}

// ---------------- fused cast fp32 -> bf16 for x, w_qkv, w_proj --------------
__global__ void cast_all(const float* __restrict__ x,  u16* __restrict__ xo,
                         const float* __restrict__ wq, u16* __restrict__ wqo,
                         const float* __restrict__ wp, u16* __restrict__ wpo) {
  const int NX = (2 * 2048 * 1024) / 4;   // float4 units
  const int NQ = (3072 * 1024) / 4;
  const int NP = (1024 * 1024) / 4;
  int i = blockIdx.x * blockDim.x + threadIdx.x;
  int stride = gridDim.x * blockDim.x;
  for (; i < NX + NQ + NP; i += stride) {
    const float4* s; uint2* d; int j;
    if (i < NX)            { s = (const float4*)x;  d = (uint2*)xo;  j = i; }
    else if (i < NX + NQ)  { s = (const float4*)wq; d = (uint2*)wqo; j = i - NX; }
    else                   { s = (const float4*)wp; d = (uint2*)wpo; j = i - NX - NQ; }
    float4 f = s[j];
    uint2 o;
    o.x = (u32)f2bf(f.x) | ((u32)f2bf(f.y) << 16);
    o.y = (u32)f2bf(f.z) | ((u32)f2bf(f.w) << 16);
    d[j] = o;
  }
}

// ---------------- bf16 MFMA GEMM: C[M,N] = A[M,K] * W[N,K]^T + bias ----------
// CHAMPION structure (44.0 us on GEMM1): BM x BN block tile, 4 waves (2x2),
// BK=32, double-buffered LDS, one barrier per K-iter, XCD-aware swizzle.
// LDS frag reads verified conflict-minimal by bank arithmetic (8 groups x 8
// lanes = 8-clk minimum) -- no swizzle needed at [.][32] row width.
template<int OUT_BF16, int BM, int BN>
__global__ __launch_bounds__(256) void gemm_nt(
    const u16* __restrict__ A, const u16* __restrict__ W,
    const float* __restrict__ bias, void* __restrict__ Cout,
    int M, int N, int K)
{
  constexpr int MT = BM / 32;             // m-tiles per wave
  constexpr int NT = BN / 32;             // n-tiles per wave
  __shared__ u16 Alds[2][BM][32];
  __shared__ u16 Blds[2][BN][32];
  const int tid  = threadIdx.x;
  const int lane = tid & 63;
  const int wave = tid >> 6;
  const int wm = (wave >> 1) * (BM / 2);
  const int wn = (wave & 1) * (BN / 2);

  const int b    = blockIdx.x;
  const int xcd  = b & 7;
  const int slot = b >> 3;
  const int npx  = (N / BN) >> 3;         // n-columns owned per XCD
  const int m0 = (slot / npx) * BM;
  const int n0 = (xcd * npx + slot % npx) * BN;

  const int quad = lane >> 4;
  const int li   = lane & 15;

  const u16* ga = &A[(size_t)(m0 + wave * (BM / 4) + (lane >> 2)) * K + (lane & 3) * 8];
  const u16* gb = &W[(size_t)(n0 + wave * (BN / 4) + (lane >> 2)) * K + (lane & 3) * 8];

  auto stage = [&](int buf, int k0) {
#pragma unroll
    for (int i = 0; i < BM / 64; i++)
      gload16(ga + (size_t)i * 16 * K + k0, &Alds[buf][wave * (BM / 4) + i * 16][0]);
#pragma unroll
    for (int i = 0; i < BN / 64; i++)
      gload16(gb + (size_t)i * 16 * K + k0, &Blds[buf][wave * (BN / 4) + i * 16][0]);
  };

  f32x4 acc[MT][NT] = {};
  const int niter = K / 32;

  stage(0, 0);                            // prologue: tile 0 -> buf 0

#pragma unroll 2
  for (int kt = 0; kt < niter; kt++) {
    __syncthreads();                      // drains tile kt (one compute phase old)
    if (kt + 1 < niter) stage((kt + 1) & 1, (kt + 1) * 32);
    const int buf = kt & 1;
    bf16x8 af[MT], bfr[NT];
#pragma unroll
    for (int t = 0; t < MT; t++)
      af[t] = *(const bf16x8*)&Alds[buf][wm + t * 16 + li][quad * 8];
#pragma unroll
    for (int t = 0; t < NT; t++)
      bfr[t] = *(const bf16x8*)&Blds[buf][wn + t * 16 + li][quad * 8];
#pragma unroll
    for (int mt = 0; mt < MT; mt++)
#pragma unroll
      for (int nt = 0; nt < NT; nt++)
        acc[mt][nt] = __builtin_amdgcn_mfma_f32_16x16x32_bf16(af[mt], bfr[nt], acc[mt][nt], 0, 0, 0);
  }

#pragma unroll
  for (int mt = 0; mt < MT; mt++)
#pragma unroll
    for (int nt = 0; nt < NT; nt++) {
      int gn = n0 + wn + nt * 16 + li;
      float bv = bias[gn];
#pragma unroll
      for (int r = 0; r < 4; r++) {
        int gm = m0 + wm + mt * 16 + quad * 4 + r;
        float v = acc[mt][nt][r] + bv;
        if (OUT_BF16)
          ((u16*)Cout)[(size_t)gm * N + gn] = f2bf(v);
        else
          ((float*)Cout)[(size_t)gm * N + gn] = v;
      }
    }
}

// ---------------- GEMM2: 128x128, BK=64, swizzled LDS, fp32 out -------------
// R8: GEMM2 runs at 1 block/CU (grid 256) so per-iter barrier drains are
// unhidden; BK=64 halves the iteration count (32 -> 16 drains). Rows are
// 128 B so the naive layout would 4-way-conflict; both-sides XOR swizzle
// (R2-verified family): 16B data-block d of row r stored at pos d^(r&7),
// gload SOURCE pre-swizzled (lane l fetches data-block (l&7)^(l>>3)), dest
// linear; frag read pos = (k*4+quad)^(li&7) -> 8 groups x 8 lanes = 8-clk
// minimum, conflict-free. 64 KB LDS is free (occupancy grid-capped at 1).
__global__ __launch_bounds__(256) void gemm_nt64(
    const u16* __restrict__ A, const u16* __restrict__ W,
    const float* __restrict__ bias, float* __restrict__ Cout,
    int M, int N, int K)
{
  __shared__ u16 Alds[2][128][64];
  __shared__ u16 Blds[2][128][64];
  const int tid  = threadIdx.x;
  const int lane = tid & 63;
  const int wave = tid >> 6;
  const int wm = (wave >> 1) * 64;
  const int wn = (wave & 1) * 64;

  const int b    = blockIdx.x;
  const int xcd  = b & 7;
  const int slot = b >> 3;
  const int npx  = (N / 128) >> 3;        // 1 for N=1024
  const int m0 = (slot / npx) * 128;
  const int n0 = (xcd * npx + slot % npx) * 128;

  const int quad = lane >> 4;
  const int li   = lane & 15;

  // staging: lane l covers row 8-group r8 = l>>3, fetches data-block (l&7)^r8
  const int r8 = lane >> 3;
  const int db = (lane & 7) ^ r8;
  const u16* ga = A + (size_t)(m0 + wave * 32 + r8) * K + db * 8;
  const u16* gb = W + (size_t)(n0 + wave * 32 + r8) * K + db * 8;

  auto stage = [&](int buf, int k0) {
#pragma unroll
    for (int i = 0; i < 4; i++)
      gload16(ga + (size_t)(i * 8) * K + k0, &Alds[buf][wave * 32 + i * 8][0]);
#pragma unroll
    for (int i = 0; i < 4; i++)
      gload16(gb + (size_t)(i * 8) * K + k0, &Blds[buf][wave * 32 + i * 8][0]);
  };

  f32x4 acc[4][4] = {};
  const int niter = K / 64;               // 16

  stage(0, 0);                            // prologue

  for (int kt = 0; kt < niter; kt++) {
    __syncthreads();                      // drains stage(kt) (compiler adds vmcnt)
    if (kt + 1 < niter) stage((kt + 1) & 1, (kt + 1) * 64);
    const int buf = kt & 1;
    bf16x8 af[4][2], bfr[4][2];
#pragma unroll
    for (int t = 0; t < 4; t++)
#pragma unroll
      for (int k = 0; k < 2; k++) {
        const int pos = ((k * 4 + quad) ^ (li & 7)) * 8;
        af[t][k]  = *(const bf16x8*)&Alds[buf][wm + t * 16 + li][pos];
        bfr[t][k] = *(const bf16x8*)&Blds[buf][wn + t * 16 + li][pos];
      }
#pragma unroll
    for (int mt = 0; mt < 4; mt++)
#pragma unroll
      for (int nt = 0; nt < 4; nt++)
#pragma unroll
        for (int k = 0; k < 2; k++)
          acc[mt][nt] = __builtin_amdgcn_mfma_f32_16x16x32_bf16(
              af[mt][k], bfr[nt][k], acc[mt][nt], 0, 0, 0);
  }

#pragma unroll
  for (int mt = 0; mt < 4; mt++)
#pragma unroll
    for (int nt = 0; nt < 4; nt++) {
      int gn = n0 + wn + nt * 16 + li;
      float bv = bias[gn];
#pragma unroll
      for (int r = 0; r < 4; r++) {
        int gm = m0 + wm + mt * 16 + quad * 4 + r;
        Cout[(size_t)gm * N + gn] = acc[mt][nt][r] + bv;
      }
    }
}

// ---------------- sliding-window flash attention -----------------------------
// CHAMPION (157.6 total): R0 structure (Klds+Vt staged, 2 barriers/tile,
// adjacent-key-pair V packing) + R5 flat-grid chunked XCD swizzle (each XCD
// owns consecutive q-tiles of the same (b,h); KV L2-resident, -5 us).
// R8's 128-query/8-wave variant regressed (+2.1 us) -> reverted.
__global__ __launch_bounds__(256, 4) void attn_kernel(const u16* __restrict__ qkv,
                                                      u16* __restrict__ aout)
{
  const int L = 2048, DQ = 3072, D = 1024;
  // chunked XCD transform on flat grid of 1024 (1024 % 8 == 0 -> bijective)
  const int bid  = blockIdx.x;
  const int wgid = (bid & 7) * 128 + (bid >> 3);
  const int qt = wgid & 31;
  const int h  = (wgid >> 5) & 15;
  const int b  = wgid >> 9;
  const int q0 = qt * 64;
  const int tid  = threadIdx.x;
  const int lane = tid & 63;
  const int wave = tid >> 6;
  const int quad = lane >> 4;
  const int li   = lane & 15;

  __shared__ u16 Klds[64][68];      // [key][e], +4 pad
  __shared__ u16 Vt[64][68];        // [e][key], +4 pad
  __shared__ u16 Plds[4][16][68];   // per-wave P transpose buffer

  const u16* base = qkv + (size_t)b * L * DQ + h * 64;

  // Q A-frags direct from global: A[m=li][k=quad*8+j], rows q0+16w+li
  bf16x8 qf[2];
  {
    const u16* qsrc = base + (size_t)(q0 + wave * 16 + li) * DQ;
    qf[0] = *(const bf16x8*)&qsrc[quad * 8];
    qf[1] = *(const bf16x8*)&qsrc[32 + quad * 8];
  }

  f32x4 O[4] = {};
  float lsum[4] = {0.f, 0.f, 0.f, 0.f};   // per-lane partial row sums

  const float scale = 0.125f;       // 1/sqrt(64)
  const int gq = q0 + wave * 16 + quad * 4;  // + r

  // staging: thread covers key rows sr2, sr2+1 (adjacent), cols sc..sc+7
  const int sr2 = (tid >> 3) * 2, sc = (tid & 7) * 8;
  const u16* ksbase = base + D;
  const u16* vsbase = base + 2 * D;
  uint4 kr0, kr1, vr0, vr1;
  auto loadkv = [&](int t) {
    int kb = q0 - 256 + t * 64;
    const u16* ks = ksbase + (size_t)kb * DQ;
    const u16* vs = vsbase + (size_t)kb * DQ;
    kr0 = *(const uint4*)&ks[(size_t)sr2 * DQ + sc];
    kr1 = *(const uint4*)&ks[(size_t)(sr2 + 1) * DQ + sc];
    vr0 = *(const uint4*)&vs[(size_t)sr2 * DQ + sc];
    vr1 = *(const uint4*)&vs[(size_t)(sr2 + 1) * DQ + sc];
  };

  const int t0 = (qt < 4) ? (4 - qt) : 0;   // first valid K-block
  loadkv(t0);

  for (int t = t0; t < 5; t++) {
    const int kb = q0 - 256 + t * 64;
    __syncthreads();                // protect LDS vs previous iter's reads
    *(uint4*)&Klds[sr2][sc]     = kr0;
    *(uint4*)&Klds[sr2 + 1][sc] = kr1;
    {
      // V transpose: pack (key sr2, key sr2+1) for each e into one b32
      u32 a0[4] = {vr0.x, vr0.y, vr0.z, vr0.w};
      u32 a1[4] = {vr1.x, vr1.y, vr1.z, vr1.w};
#pragma unroll
      for (int j2 = 0; j2 < 4; j2++) {
        u32 lo0 = a0[j2] & 0xffffu, hi0 = a0[j2] >> 16;
        u32 lo1 = a1[j2] & 0xffffu, hi1 = a1[j2] >> 16;
        *(u32*)&Vt[sc + 2 * j2][sr2]     = lo0 | (lo1 << 16);
        *(u32*)&Vt[sc + 2 * j2 + 1][sr2] = hi0 | (hi1 << 16);
      }
    }
    __syncthreads();
    if (t + 1 < 5) loadkv(t + 1);   // prefetch overlaps with compute below

    // S = Q K^T : 16 rows x 64 keys
    f32x4 sacc[4] = {};
#pragma unroll
    for (int nt = 0; nt < 4; nt++) {
      bf16x8 kf0 = *(const bf16x8*)&Klds[nt * 16 + li][quad * 8];
      bf16x8 kf1 = *(const bf16x8*)&Klds[nt * 16 + li][32 + quad * 8];
      sacc[nt] = __builtin_amdgcn_mfma_f32_16x16x32_bf16(qf[0], kf0, sacc[nt], 0, 0, 0);
      sacc[nt] = __builtin_amdgcn_mfma_f32_16x16x32_bf16(qf[1], kf1, sacc[nt], 0, 0, 0);
    }

    // mask + fixed-shift exp; accumulate per-lane partial sums; write P
#pragma unroll
    for (int nt = 0; nt < 4; nt++) {
      int gj = kb + nt * 16 + li;
#pragma unroll
      for (int r = 0; r < 4; r++) {
        bool masked = (gj > gq + r) || ((gq + r) - gj >= 256);
        float p = masked ? 0.f : __expf(sacc[nt][r] * scale - 12.f);
        lsum[r] += p;
        Plds[wave][quad * 4 + r][nt * 16 + li] = f2bf(p);
      }
    }

    // O += P V : A = P[m=li][k=key], B = Vt[n=e=li'][k=key] (b128 reads)
    bf16x8 pf0 = *(const bf16x8*)&Plds[wave][li][quad * 8];
    bf16x8 pf1 = *(const bf16x8*)&Plds[wave][li][32 + quad * 8];
#pragma unroll
    for (int nt = 0; nt < 4; nt++) {
      bf16x8 vb0 = *(const bf16x8*)&Vt[nt * 16 + li][quad * 8];
      bf16x8 vb1 = *(const bf16x8*)&Vt[nt * 16 + li][32 + quad * 8];
      O[nt] = __builtin_amdgcn_mfma_f32_16x16x32_bf16(pf0, vb0, O[nt], 0, 0, 0);
      O[nt] = __builtin_amdgcn_mfma_f32_16x16x32_bf16(pf1, vb1, O[nt], 0, 0, 0);
    }
  }

  // epilogue: reduce l over the 16-lane li group (once), then O/l -> aout
#pragma unroll
  for (int d = 1; d < 16; d <<= 1)
#pragma unroll
    for (int r = 0; r < 4; r++)
      lsum[r] += __shfl_xor(lsum[r], d, 64);
#pragma unroll
  for (int r = 0; r < 4; r++) {
    float inv = 1.f / lsum[r];
#pragma unroll
    for (int nt = 0; nt < 4; nt++)
      aout[(size_t)(b * L + gq + r) * D + h * 64 + nt * 16 + li] = f2bf(O[nt][r] * inv);
  }
}

// ---------------- launcher ---------------------------------------------------
extern "C" void kernel_launch(void* const* d_in, const int* in_sizes, int n_in,
                              void* d_out, int out_size, void* d_ws, size_t ws_size,
                              hipStream_t stream) {
  const float* x      = (const float*)d_in[0];
  const float* w_qkv  = (const float*)d_in[1];
  const float* b_qkv  = (const float*)d_in[2];
  const float* w_proj = (const float*)d_in[3];
  const float* b_proj = (const float*)d_in[4];
  float* out = (float*)d_out;

  char* ws = (char*)d_ws;
  u16* x_bf     = (u16*)(ws);                         //  8 MB: [4096,1024] bf16
  u16* wqkv_bf  = (u16*)(ws + ((size_t)8  << 20));    //  6 MB: [3072,1024] bf16
  u16* wproj_bf = (u16*)(ws + ((size_t)14 << 20));    //  2 MB: [1024,1024] bf16
  u16* qkv_bf   = (u16*)(ws + ((size_t)16 << 20));    // 24 MB: [4096,3072] bf16
  u16* attn_bf  = (u16*)(ws + ((size_t)40 << 20));    //  8 MB: [4096,1024] bf16

  cast_all<<<1024, 256, 0, stream>>>(x, x_bf, w_qkv, wqkv_bf, w_proj, wproj_bf);

  // GEMM1: 44.0 us champion (128x128, 768 blocks, 3/CU)
  gemm_nt<1, 128, 128><<<(4096 / 128) * (3072 / 128), 256, 0, stream>>>(
      x_bf, wqkv_bf, b_qkv, qkv_bf, 4096, 3072, 1024);

  // attn: champion (1024 blocks x 256 thr, chunked XCD swizzle)
  attn_kernel<<<1024, 256, 0, stream>>>(qkv_bf, attn_bf);

  // GEMM2: BK=64 swizzled variant (16 barrier-drains instead of 32)
  gemm_nt64<<<(4096 / 128) * (1024 / 128), 256, 0, stream>>>(
      attn_bf, wproj_bf, b_proj, out, 4096, 1024, 1024);
}

// Round 10
// 157.057 us; speedup vs baseline: 1.0170x; 1.0021x over previous
//
#include <hip/hip_runtime.h>

typedef __bf16 bf16x8 __attribute__((ext_vector_type(8)));
typedef float f32x4 __attribute__((ext_vector_type(4)));
typedef unsigned short u16;
typedef unsigned int u32;

// native HW bf16 convert (gfx950 v_cvt_pk_bf16_f32, RNE — same rounding as
// the old 4-op manual path, 1 VALU op instead of 4)
__device__ __forceinline__ u16 f2bf(float f) {
  return __builtin_bit_cast(u16, (__bf16)f);
}

// async global->LDS, 16B/lane. One call = 64 lanes x 16B = 1024B.
// LDS dest = wave-uniform base + lane*16 (HW rule).
__device__ __forceinline__ void gload16(const u16* g, u16* lds_base) {
  __builtin_amdgcn_global_load_lds(
      (const __attribute__((address_space(1))) void*)g,
      (__attribute__((address_space(3))) void*)lds_base, 16, 0, 0);
}

// ---------------- fused cast fp32 -> bf16 for x, w_qkv, w_proj --------------
__global__ void cast_all(const float* __restrict__ x,  u16* __restrict__ xo,
                         const float* __restrict__ wq, u16* __restrict__ wqo,
                         const float* __restrict__ wp, u16* __restrict__ wpo) {
  const int NX = (2 * 2048 * 1024) / 4;   // float4 units
  const int NQ = (3072 * 1024) / 4;
  const int NP = (1024 * 1024) / 4;
  int i = blockIdx.x * blockDim.x + threadIdx.x;
  int stride = gridDim.x * blockDim.x;
  for (; i < NX + NQ + NP; i += stride) {
    const float4* s; uint2* d; int j;
    if (i < NX)            { s = (const float4*)x;  d = (uint2*)xo;  j = i; }
    else if (i < NX + NQ)  { s = (const float4*)wq; d = (uint2*)wqo; j = i - NX; }
    else                   { s = (const float4*)wp; d = (uint2*)wpo; j = i - NX - NQ; }
    float4 f = s[j];
    uint2 o;
    o.x = (u32)f2bf(f.x) | ((u32)f2bf(f.y) << 16);
    o.y = (u32)f2bf(f.z) | ((u32)f2bf(f.w) << 16);
    d[j] = o;
  }
}

// ---------------- bf16 MFMA GEMM: C[M,N] = A[M,K] * W[N,K]^T + bias ----------
// CHAMPION structure (44.0 us on GEMM1): BM x BN block tile, 4 waves (2x2),
// BK=32, double-buffered LDS, one barrier per K-iter, XCD-aware swizzle.
template<int OUT_BF16, int BM, int BN>
__global__ __launch_bounds__(256) void gemm_nt(
    const u16* __restrict__ A, const u16* __restrict__ W,
    const float* __restrict__ bias, void* __restrict__ Cout,
    int M, int N, int K)
{
  constexpr int MT = BM / 32;             // m-tiles per wave
  constexpr int NT = BN / 32;             // n-tiles per wave
  __shared__ u16 Alds[2][BM][32];
  __shared__ u16 Blds[2][BN][32];
  const int tid  = threadIdx.x;
  const int lane = tid & 63;
  const int wave = tid >> 6;
  const int wm = (wave >> 1) * (BM / 2);
  const int wn = (wave & 1) * (BN / 2);

  const int b    = blockIdx.x;
  const int xcd  = b & 7;
  const int slot = b >> 3;
  const int npx  = (N / BN) >> 3;         // n-columns owned per XCD
  const int m0 = (slot / npx) * BM;
  const int n0 = (xcd * npx + slot % npx) * BN;

  const int quad = lane >> 4;
  const int li   = lane & 15;

  const u16* ga = &A[(size_t)(m0 + wave * (BM / 4) + (lane >> 2)) * K + (lane & 3) * 8];
  const u16* gb = &W[(size_t)(n0 + wave * (BN / 4) + (lane >> 2)) * K + (lane & 3) * 8];

  auto stage = [&](int buf, int k0) {
#pragma unroll
    for (int i = 0; i < BM / 64; i++)
      gload16(ga + (size_t)i * 16 * K + k0, &Alds[buf][wave * (BM / 4) + i * 16][0]);
#pragma unroll
    for (int i = 0; i < BN / 64; i++)
      gload16(gb + (size_t)i * 16 * K + k0, &Blds[buf][wave * (BN / 4) + i * 16][0]);
  };

  f32x4 acc[MT][NT] = {};
  const int niter = K / 32;

  stage(0, 0);                            // prologue: tile 0 -> buf 0

#pragma unroll 2
  for (int kt = 0; kt < niter; kt++) {
    __syncthreads();                      // drains tile kt (one compute phase old)
    if (kt + 1 < niter) stage((kt + 1) & 1, (kt + 1) * 32);
    const int buf = kt & 1;
    bf16x8 af[MT], bfr[NT];
#pragma unroll
    for (int t = 0; t < MT; t++)
      af[t] = *(const bf16x8*)&Alds[buf][wm + t * 16 + li][quad * 8];
#pragma unroll
    for (int t = 0; t < NT; t++)
      bfr[t] = *(const bf16x8*)&Blds[buf][wn + t * 16 + li][quad * 8];
#pragma unroll
    for (int mt = 0; mt < MT; mt++)
#pragma unroll
      for (int nt = 0; nt < NT; nt++)
        acc[mt][nt] = __builtin_amdgcn_mfma_f32_16x16x32_bf16(af[mt], bfr[nt], acc[mt][nt], 0, 0, 0);
  }

#pragma unroll
  for (int mt = 0; mt < MT; mt++)
#pragma unroll
    for (int nt = 0; nt < NT; nt++) {
      int gn = n0 + wn + nt * 16 + li;
      float bv = bias[gn];
#pragma unroll
      for (int r = 0; r < 4; r++) {
        int gm = m0 + wm + mt * 16 + quad * 4 + r;
        float v = acc[mt][nt][r] + bv;
        if (OUT_BF16)
          ((u16*)Cout)[(size_t)gm * N + gn] = f2bf(v);
        else
          ((float*)Cout)[(size_t)gm * N + gn] = v;
      }
    }
}

// ---------------- GEMM2: 128x128, BK=64, swizzled LDS, fp32 out -------------
// R8/R9: BK=64 halves iteration count; measured ~neutral-positive vs BK=32.
// Both-sides XOR swizzle (R2-verified family) keeps b128 reads conflict-free.
__global__ __launch_bounds__(256) void gemm_nt64(
    const u16* __restrict__ A, const u16* __restrict__ W,
    const float* __restrict__ bias, float* __restrict__ Cout,
    int M, int N, int K)
{
  __shared__ u16 Alds[2][128][64];
  __shared__ u16 Blds[2][128][64];
  const int tid  = threadIdx.x;
  const int lane = tid & 63;
  const int wave = tid >> 6;
  const int wm = (wave >> 1) * 64;
  const int wn = (wave & 1) * 64;

  const int b    = blockIdx.x;
  const int xcd  = b & 7;
  const int slot = b >> 3;
  const int npx  = (N / 128) >> 3;        // 1 for N=1024
  const int m0 = (slot / npx) * 128;
  const int n0 = (xcd * npx + slot % npx) * 128;

  const int quad = lane >> 4;
  const int li   = lane & 15;

  // staging: lane l covers row 8-group r8 = l>>3, fetches data-block (l&7)^r8
  const int r8 = lane >> 3;
  const int db = (lane & 7) ^ r8;
  const u16* ga = A + (size_t)(m0 + wave * 32 + r8) * K + db * 8;
  const u16* gb = W + (size_t)(n0 + wave * 32 + r8) * K + db * 8;

  auto stage = [&](int buf, int k0) {
#pragma unroll
    for (int i = 0; i < 4; i++)
      gload16(ga + (size_t)(i * 8) * K + k0, &Alds[buf][wave * 32 + i * 8][0]);
#pragma unroll
    for (int i = 0; i < 4; i++)
      gload16(gb + (size_t)(i * 8) * K + k0, &Blds[buf][wave * 32 + i * 8][0]);
  };

  f32x4 acc[4][4] = {};
  const int niter = K / 64;               // 16

  stage(0, 0);                            // prologue

  for (int kt = 0; kt < niter; kt++) {
    __syncthreads();                      // drains stage(kt)
    if (kt + 1 < niter) stage((kt + 1) & 1, (kt + 1) * 64);
    const int buf = kt & 1;
    bf16x8 af[4][2], bfr[4][2];
#pragma unroll
    for (int t = 0; t < 4; t++)
#pragma unroll
      for (int k = 0; k < 2; k++) {
        const int pos = ((k * 4 + quad) ^ (li & 7)) * 8;
        af[t][k]  = *(const bf16x8*)&Alds[buf][wm + t * 16 + li][pos];
        bfr[t][k] = *(const bf16x8*)&Blds[buf][wn + t * 16 + li][pos];
      }
#pragma unroll
    for (int mt = 0; mt < 4; mt++)
#pragma unroll
      for (int nt = 0; nt < 4; nt++)
#pragma unroll
        for (int k = 0; k < 2; k++)
          acc[mt][nt] = __builtin_amdgcn_mfma_f32_16x16x32_bf16(
              af[mt][k], bfr[nt][k], acc[mt][nt], 0, 0, 0);
  }

#pragma unroll
  for (int mt = 0; mt < 4; mt++)
#pragma unroll
    for (int nt = 0; nt < 4; nt++) {
      int gn = n0 + wn + nt * 16 + li;
      float bv = bias[gn];
#pragma unroll
      for (int r = 0; r < 4; r++) {
        int gm = m0 + wm + mt * 16 + quad * 4 + r;
        Cout[(size_t)gm * N + gn] = acc[mt][nt][r] + bv;
      }
    }
}

// ---------------- sliding-window flash attention -----------------------------
// CHAMPION structure + R9 VALU trims:
//  * exp2-direct softmax: p = exp2(fma(s, 0.125*log2e, -12*log2e)) — 2 VALU
//    ops vs 4 (v_exp_f32 IS 2^x; scale+shift folded into one fma).
//  * native bf16 cvt (f2bf above) for the 16 P-writes + epilogue.
//  * mask specialization: tiles t=1..3 are FULLY unmasked for every wave
//    (window boundary: max query-key distance = 255 < 256, causal edge only
//    at t=4, window tail only at t=0) -> mask math on 2 of 5 tiles only.
__global__ __launch_bounds__(256, 4) void attn_kernel(const u16* __restrict__ qkv,
                                                      u16* __restrict__ aout)
{
  const int L = 2048, DQ = 3072, D = 1024;
  // chunked XCD transform on flat grid of 1024 (1024 % 8 == 0 -> bijective)
  const int bid  = blockIdx.x;
  const int wgid = (bid & 7) * 128 + (bid >> 3);
  const int qt = wgid & 31;
  const int h  = (wgid >> 5) & 15;
  const int b  = wgid >> 9;
  const int q0 = qt * 64;
  const int tid  = threadIdx.x;
  const int lane = tid & 63;
  const int wave = tid >> 6;
  const int quad = lane >> 4;
  const int li   = lane & 15;

  __shared__ u16 Klds[64][68];      // [key][e], +4 pad
  __shared__ u16 Vt[64][68];        // [e][key], +4 pad
  __shared__ u16 Plds[4][16][68];   // per-wave P transpose buffer

  const u16* base = qkv + (size_t)b * L * DQ + h * 64;

  // Q A-frags direct from global: A[m=li][k=quad*8+j], rows q0+16w+li
  bf16x8 qf[2];
  {
    const u16* qsrc = base + (size_t)(q0 + wave * 16 + li) * DQ;
    qf[0] = *(const bf16x8*)&qsrc[quad * 8];
    qf[1] = *(const bf16x8*)&qsrc[32 + quad * 8];
  }

  f32x4 O[4] = {};
  float lsum[4] = {0.f, 0.f, 0.f, 0.f};   // per-lane partial row sums

  const float C1 = 0.18033688011112042f;  // 0.125 * log2(e)
  const float C2 = 17.312340490667562f;   // 12 * log2(e)
  const int gq = q0 + wave * 16 + quad * 4;  // + r

  // staging: thread covers key rows sr2, sr2+1 (adjacent), cols sc..sc+7
  const int sr2 = (tid >> 3) * 2, sc = (tid & 7) * 8;
  const u16* ksbase = base + D;
  const u16* vsbase = base + 2 * D;
  uint4 kr0, kr1, vr0, vr1;
  auto loadkv = [&](int t) {
    int kb = q0 - 256 + t * 64;
    const u16* ks = ksbase + (size_t)kb * DQ;
    const u16* vs = vsbase + (size_t)kb * DQ;
    kr0 = *(const uint4*)&ks[(size_t)sr2 * DQ + sc];
    kr1 = *(const uint4*)&ks[(size_t)(sr2 + 1) * DQ + sc];
    vr0 = *(const uint4*)&vs[(size_t)sr2 * DQ + sc];
    vr1 = *(const uint4*)&vs[(size_t)(sr2 + 1) * DQ + sc];
  };

  const int t0 = (qt < 4) ? (4 - qt) : 0;   // first valid K-block
  loadkv(t0);

  for (int t = t0; t < 5; t++) {
    const int kb = q0 - 256 + t * 64;
    __syncthreads();                // protect LDS vs previous iter's reads
    *(uint4*)&Klds[sr2][sc]     = kr0;
    *(uint4*)&Klds[sr2 + 1][sc] = kr1;
    {
      // V transpose: pack (key sr2, key sr2+1) for each e into one b32
      u32 a0[4] = {vr0.x, vr0.y, vr0.z, vr0.w};
      u32 a1[4] = {vr1.x, vr1.y, vr1.z, vr1.w};
#pragma unroll
      for (int j2 = 0; j2 < 4; j2++) {
        u32 lo0 = a0[j2] & 0xffffu, hi0 = a0[j2] >> 16;
        u32 lo1 = a1[j2] & 0xffffu, hi1 = a1[j2] >> 16;
        *(u32*)&Vt[sc + 2 * j2][sr2]     = lo0 | (lo1 << 16);
        *(u32*)&Vt[sc + 2 * j2 + 1][sr2] = hi0 | (hi1 << 16);
      }
    }
    __syncthreads();
    if (t + 1 < 5) loadkv(t + 1);   // prefetch overlaps with compute below

    // S = Q K^T : 16 rows x 64 keys
    f32x4 sacc[4] = {};
#pragma unroll
    for (int nt = 0; nt < 4; nt++) {
      bf16x8 kf0 = *(const bf16x8*)&Klds[nt * 16 + li][quad * 8];
      bf16x8 kf1 = *(const bf16x8*)&Klds[nt * 16 + li][32 + quad * 8];
      sacc[nt] = __builtin_amdgcn_mfma_f32_16x16x32_bf16(qf[0], kf0, sacc[nt], 0, 0, 0);
      sacc[nt] = __builtin_amdgcn_mfma_f32_16x16x32_bf16(qf[1], kf1, sacc[nt], 0, 0, 0);
    }

    // softmax: exp2-direct; mask only where needed (t==0 window tail,
    // t==4 causal edge; t=1..3 proven fully unmasked)
    const bool needmask = (t == 0) || (t == 4);
#pragma unroll
    for (int nt = 0; nt < 4; nt++) {
      int gj = kb + nt * 16 + li;
#pragma unroll
      for (int r = 0; r < 4; r++) {
        float e = __builtin_amdgcn_exp2f(__builtin_fmaf(sacc[nt][r], C1, -C2));
        float p;
        if (needmask) {
          bool masked = (gj > gq + r) || ((gq + r) - gj >= 256);
          p = masked ? 0.f : e;
        } else {
          p = e;
        }
        lsum[r] += p;
        Plds[wave][quad * 4 + r][nt * 16 + li] = f2bf(p);
      }
    }

    // O += P V : A = P[m=li][k=key], B = Vt[n=e=li'][k=key] (b128 reads)
    bf16x8 pf0 = *(const bf16x8*)&Plds[wave][li][quad * 8];
    bf16x8 pf1 = *(const bf16x8*)&Plds[wave][li][32 + quad * 8];
#pragma unroll
    for (int nt = 0; nt < 4; nt++) {
      bf16x8 vb0 = *(const bf16x8*)&Vt[nt * 16 + li][quad * 8];
      bf16x8 vb1 = *(const bf16x8*)&Vt[nt * 16 + li][32 + quad * 8];
      O[nt] = __builtin_amdgcn_mfma_f32_16x16x32_bf16(pf0, vb0, O[nt], 0, 0, 0);
      O[nt] = __builtin_amdgcn_mfma_f32_16x16x32_bf16(pf1, vb1, O[nt], 0, 0, 0);
    }
  }

  // epilogue: reduce l over the 16-lane li group (once), then O/l -> aout
#pragma unroll
  for (int d = 1; d < 16; d <<= 1)
#pragma unroll
    for (int r = 0; r < 4; r++)
      lsum[r] += __shfl_xor(lsum[r], d, 64);
#pragma unroll
  for (int r = 0; r < 4; r++) {
    float inv = 1.f / lsum[r];
#pragma unroll
    for (int nt = 0; nt < 4; nt++)
      aout[(size_t)(b * L + gq + r) * D + h * 64 + nt * 16 + li] = f2bf(O[nt][r] * inv);
  }
}

// ---------------- launcher ---------------------------------------------------
extern "C" void kernel_launch(void* const* d_in, const int* in_sizes, int n_in,
                              void* d_out, int out_size, void* d_ws, size_t ws_size,
                              hipStream_t stream) {
  const float* x      = (const float*)d_in[0];
  const float* w_qkv  = (const float*)d_in[1];
  const float* b_qkv  = (const float*)d_in[2];
  const float* w_proj = (const float*)d_in[3];
  const float* b_proj = (const float*)d_in[4];
  float* out = (float*)d_out;

  char* ws = (char*)d_ws;
  u16* x_bf     = (u16*)(ws);                         //  8 MB: [4096,1024] bf16
  u16* wqkv_bf  = (u16*)(ws + ((size_t)8  << 20));    //  6 MB: [3072,1024] bf16
  u16* wproj_bf = (u16*)(ws + ((size_t)14 << 20));    //  2 MB: [1024,1024] bf16
  u16* qkv_bf   = (u16*)(ws + ((size_t)16 << 20));    // 24 MB: [4096,3072] bf16
  u16* attn_bf  = (u16*)(ws + ((size_t)40 << 20));    //  8 MB: [4096,1024] bf16

  cast_all<<<2048, 256, 0, stream>>>(x, x_bf, w_qkv, wqkv_bf, w_proj, wproj_bf);

  // GEMM1: 44.0 us champion (128x128, 768 blocks, 3/CU)
  gemm_nt<1, 128, 128><<<(4096 / 128) * (3072 / 128), 256, 0, stream>>>(
      x_bf, wqkv_bf, b_qkv, qkv_bf, 4096, 3072, 1024);

  // attn: champion (1024 blocks x 256 thr, chunked XCD swizzle) + VALU trims
  attn_kernel<<<1024, 256, 0, stream>>>(qkv_bf, attn_bf);

  // GEMM2: BK=64 swizzled variant
  gemm_nt64<<<(4096 / 128) * (1024 / 128), 256, 0, stream>>>(
      attn_bf, wproj_bf, b_proj, out, 4096, 1024, 1024);
}